// Round 10
// baseline (372.746 us; speedup 1.0000x reference)
//
#include <hip/hip_runtime.h>
#include <hip/hip_bf16.h>

typedef __hip_bfloat16 bf16_t;
typedef __bf16 bf16x8 __attribute__((ext_vector_type(8)));
typedef float f32x4 __attribute__((ext_vector_type(4)));

#define LQ 512
#define LK 4096
#define BATCH 4
#define DMODEL 512
#define NHEAD 8
#define HEADDIM 64
#define DFF 2048
#define LN_EPS 1e-5f

__device__ inline float tofl(float x) { return x; }
__device__ inline float tofl(bf16_t x) { return __bfloat162float(x); }
__device__ inline void stfl(float* p, float v) { *p = v; }
__device__ inline void stfl(bf16_t* p, float v) { *p = __float2bfloat16(v); }

// async global->LDS 16B copy: LDS dest = wave-uniform base + lane*16
__device__ __forceinline__ void gld_lds16(const bf16_t* g, void* lds_base) {
    __builtin_amdgcn_global_load_lds(
        (const __attribute__((address_space(1))) uint32_t*)g,
        (__attribute__((address_space(3))) uint32_t*)lds_base, 16, 0, 0);
}

// ---------- prep: all weight conversions + attn_out zero-fill ----------
__global__ void prep_kernel(const float* __restrict__ s0, const float* __restrict__ s1,
                            const float* __restrict__ s2, const float* __restrict__ s3,
                            const float* __restrict__ s4, const float* __restrict__ s5,
                            bf16_t* __restrict__ wqkvo, bf16_t* __restrict__ w1bf,
                            bf16_t* __restrict__ w2bf, float* __restrict__ zbuf) {
    int bid = blockIdx.x;
    int tid = threadIdx.x;
    if (bid < 3072) {
        int t = bid * 256 + tid;
        int which = t >> 16;            // 0..11, 262144 elements each
        int idx = (t & 65535) * 4;
        const float* s; bf16_t* d;
        if (which < 4) {
            s = (which == 0 ? s0 : which == 1 ? s1 : which == 2 ? s2 : s3) ;
            d = wqkvo + (size_t)which * 262144;
        } else if (which < 8) {
            s = s4 + (size_t)(which - 4) * 262144;
            d = w1bf + (size_t)(which - 4) * 262144;
        } else {
            s = s5 + (size_t)(which - 8) * 262144;
            d = w2bf + (size_t)(which - 8) * 262144;
        }
        float4 v = *(const float4*)(s + idx);
        d[idx + 0] = __float2bfloat16(v.x);
        d[idx + 1] = __float2bfloat16(v.y);
        d[idx + 2] = __float2bfloat16(v.z);
        d[idx + 3] = __float2bfloat16(v.w);
    } else {
        size_t i = ((size_t)(bid - 3072) * 256 + tid) * 4;
        float4 z = {0.f, 0.f, 0.f, 0.f};
        *(float4*)(zbuf + i) = z;
    }
}

// ---------- LayerNorm (generic, templated) ----------
template <typename TOUT, bool DUAL>
__global__ void ln_kernel(const float* __restrict__ in, const float* __restrict__ w,
                          const float* __restrict__ b, TOUT* __restrict__ out1,
                          float* __restrict__ out2) {
    __shared__ float red[256];
    const int row = blockIdx.x;
    const int tid = threadIdx.x;
    const float* x = in + (size_t)row * DMODEL;
    float v0 = x[tid];
    float v1 = x[tid + 256];

    red[tid] = v0 + v1;
    __syncthreads();
    for (int s = 128; s > 0; s >>= 1) { if (tid < s) red[tid] += red[tid + s]; __syncthreads(); }
    float mu = red[0] * (1.0f / DMODEL);
    __syncthreads();

    float d0 = v0 - mu, d1 = v1 - mu;
    red[tid] = d0 * d0 + d1 * d1;
    __syncthreads();
    for (int s = 128; s > 0; s >>= 1) { if (tid < s) red[tid] += red[tid + s]; __syncthreads(); }
    float inv = rsqrtf(red[0] * (1.0f / DMODEL) + LN_EPS);

    float r0 = d0 * inv * w[tid] + b[tid];
    float r1 = d1 * inv * w[tid + 256] + b[tid + 256];
    TOUT* o = out1 + (size_t)row * DMODEL;
    stfl(&o[tid], r0);
    stfl(&o[tid + 256], r1);
    if (DUAL) {
        float* o2 = out2 + (size_t)row * DMODEL;
        o2[tid] = r0;
        o2[tid + 256] = r1;
    }
}

// ---------- fused LN1 + LN2 ----------
__global__ void ln12_kernel(const float* __restrict__ tgt, const float* __restrict__ memory,
                            const float* __restrict__ w1, const float* __restrict__ b1,
                            const float* __restrict__ w2, const float* __restrict__ b2,
                            bf16_t* __restrict__ t_bf, float* __restrict__ t_f32,
                            bf16_t* __restrict__ m_buf) {
    __shared__ float red[256];
    const int row = blockIdx.x;
    const int tid = threadIdx.x;
    const float* in; const float* w; const float* b;
    bf16_t* o1; float* o2; bool dual;
    if (row < 2048) {
        in = tgt + (size_t)row * DMODEL; w = w1; b = b1;
        o1 = t_bf + (size_t)row * DMODEL; o2 = t_f32 + (size_t)row * DMODEL; dual = true;
    } else {
        int r2 = row - 2048;
        in = memory + (size_t)r2 * DMODEL; w = w2; b = b2;
        o1 = m_buf + (size_t)r2 * DMODEL; o2 = nullptr; dual = false;
    }
    float v0 = in[tid];
    float v1 = in[tid + 256];
    red[tid] = v0 + v1;
    __syncthreads();
    for (int s = 128; s > 0; s >>= 1) { if (tid < s) red[tid] += red[tid + s]; __syncthreads(); }
    float mu = red[0] * (1.0f / DMODEL);
    __syncthreads();
    float d0 = v0 - mu, d1 = v1 - mu;
    red[tid] = d0 * d0 + d1 * d1;
    __syncthreads();
    for (int s = 128; s > 0; s >>= 1) { if (tid < s) red[tid] += red[tid + s]; __syncthreads(); }
    float inv = rsqrtf(red[0] * (1.0f / DMODEL) + LN_EPS);
    float r0 = d0 * inv * w[tid] + b[tid];
    float r1 = d1 * inv * w[tid + 256] + b[tid + 256];
    o1[tid] = __float2bfloat16(r0);
    o1[tid + 256] = __float2bfloat16(r1);
    if (dual) {
        o2[tid] = r0;
        o2[tid + 256] = r1;
    }
}

// ---------- MFMA GEMM with global_load_lds staging ----------
// Tile 128 x TN (TN=128 or 64), BK=64. LDS layout: slot = kc*ROWS + r (16B units).
template <int TN, typename TC, bool RELU, bool RESID>
__global__ __launch_bounds__(256) void gemm_mfma(
        const bf16_t* __restrict__ A, const bf16_t* __restrict__ B,
        const float* __restrict__ bias, const float* __restrict__ resid,
        TC* __restrict__ C, int M, int N, int K) {
    __shared__ uint4 As4[1024];          // 128 rows x 8 kc
    __shared__ uint4 Bs4[TN * 8];        // TN rows x 8 kc

    const int tid = threadIdx.x;
    const int lane = tid & 63;
    const int wave = tid >> 6;
    const int row16 = lane & 15;
    const int quad = lane >> 4;
    const int n0 = blockIdx.x * TN;
    const int m0 = blockIdx.y * 128;

    constexpr int MI = (TN == 128) ? 4 : 2;           // 16-row frags per wave in M
    const int wy = (TN == 128) ? (wave >> 1) : wave;
    const int wx = (TN == 128) ? (wave & 1) : 0;
    const int m_base = wy * ((TN == 128) ? 64 : 32);
    const int n_base = wx * 64;

    const bf16_t* AsE = (const bf16_t*)As4;
    const bf16_t* BsE = (const bf16_t*)Bs4;

    f32x4 acc[MI][4] = {};

    for (int k0 = 0; k0 < K; k0 += 64) {
        // stage A: 1024 slots; wave handles 64 contiguous slots per issue
#pragma unroll
        for (int it = 0; it < 4; it++) {
            int base = (it * 4 + wave) * 64;
            int slot = base + lane;
            int kc = slot >> 7, r = slot & 127;
            gld_lds16(A + (size_t)(m0 + r) * K + k0 + kc * 8, &As4[base]);
        }
        // stage B: TN*8 slots
#pragma unroll
        for (int it = 0; it < TN / 32; it++) {
            int base = (it * 4 + wave) * 64;
            int slot = base + lane;
            int kc = slot / TN, r = slot % TN;
            gld_lds16(B + (size_t)(n0 + r) * K + k0 + kc * 8, &Bs4[base]);
        }
        __syncthreads();
#pragma unroll
        for (int s = 0; s < 2; s++) {
            bf16x8 af[MI], bfr[4];
#pragma unroll
            for (int i = 0; i < MI; i++)
                af[i] = *(const bf16x8*)&AsE[((s * 4 + quad) * 128 + m_base + i * 16 + row16) * 8];
#pragma unroll
            for (int j = 0; j < 4; j++)
                bfr[j] = *(const bf16x8*)&BsE[((s * 4 + quad) * TN + n_base + j * 16 + row16) * 8];
#pragma unroll
            for (int i = 0; i < MI; i++)
#pragma unroll
                for (int j = 0; j < 4; j++)
                    acc[i][j] = __builtin_amdgcn_mfma_f32_16x16x32_bf16(af[i], bfr[j], acc[i][j], 0, 0, 0);
        }
        __syncthreads();
    }

#pragma unroll
    for (int i = 0; i < MI; i++) {
#pragma unroll
        for (int j = 0; j < 4; j++) {
            int col = n0 + n_base + j * 16 + row16;
            float bsv = bias[col];
#pragma unroll
            for (int r = 0; r < 4; r++) {
                int row = m0 + m_base + i * 16 + quad * 4 + r;
                float val = acc[i][j][r] + bsv;
                if (RESID) val += resid[(size_t)row * N + col];
                if (RELU) val = fmaxf(val, 0.0f);
                stfl(&C[(size_t)row * N + col], val);
            }
        }
    }
}

// ---------- transpose: in[(key*4+b)*512 + c] -> out[(b*512+c)*4096 + key] ----------
__global__ __launch_bounds__(256) void transpose_kv(const bf16_t* __restrict__ kb,
                                                    bf16_t* __restrict__ kT) {
    __shared__ bf16_t tile[64][80];
    const int kt = blockIdx.x * 64;
    const int ct = blockIdx.y * 64;
    const int b  = blockIdx.z;
    const int t = threadIdx.x;
    {
        int kl = t >> 2, cl = (t & 3) * 16;
        const bf16_t* src = kb + ((size_t)(kt + kl) * 4 + b) * 512 + ct + cl;
        *(uint4*)&tile[kl][cl]     = *(const uint4*)src;
        *(uint4*)&tile[kl][cl + 8] = *(const uint4*)(src + 8);
    }
    __syncthreads();
    {
        int cl2 = t >> 2, ks = (t & 3) * 16;
        __attribute__((aligned(16))) bf16_t vals[16];
#pragma unroll
        for (int j = 0; j < 16; j++) vals[j] = tile[ks + j][cl2];
        bf16_t* dst = kT + ((size_t)b * 512 + ct + cl2) * 4096 + kt + ks;
        *(uint4*)dst       = *(const uint4*)&vals[0];
        *(uint4*)(dst + 8) = *(const uint4*)&vals[8];
    }
}

// ---------- MFMA flash attention, single pass (unchanged from R9) ----------
__global__ __launch_bounds__(256, 2) void attn_mfma(
        const bf16_t* __restrict__ qb,   // [2048,512] rows (q*4+b)
        const bf16_t* __restrict__ kb,   // [16384,512] rows (key*4+b)
        const bf16_t* __restrict__ vT,   // [4][512][4096]
        bf16_t* __restrict__ ctx,        // [2048,512]
        float* __restrict__ attn_out) {  // [4][512][4096], pre-zeroed
    const int d = blockIdx.x;
    const int g = d & 7;
    const int b = g >> 1;
    const int qhalf = g & 1;
    const int i_in = d >> 3;
    const int hg = i_in & 1;
    const int qt = qhalf * 32 + (i_in >> 1);
    const int q0 = qt * 8;
    const int tid = threadIdx.x;
    const int lane = tid & 63;
    const int w = tid >> 6;
    const int h = hg * 4 + w;
    const int hoffg = h * HEADDIM;
    const int hl = w * HEADDIM;
    const int row16 = lane & 15;
    const int quad = lane >> 4;

    __align__(16) __shared__ bf16_t Qs[8][264];
    __align__(16) __shared__ bf16_t Zrow[904];
    __align__(16) __shared__ bf16_t Ps[4][8][904];
    __shared__ float Ls[4][8];

    int us; { int s = q0 * 8, e = s + 827; if (e > 4095) s = 3268; us = s; }
    int sq[4], eq[4];
#pragma unroll
    for (int r = 0; r < 4; r++) {
        int ql = quad * 4 + r;
        if (ql < 8) {
            int s = (q0 + ql) * 8, e = s + 827;
            if (e > 4095) { s = 3268; e = 4096; }
            sq[r] = s; eq[r] = e;
        } else { sq[r] = 0; eq[r] = 0; }
    }

    {
        int r = tid >> 5, coff = (tid & 31) * 8;
        *(uint4*)&Qs[r][coff] =
            *(const uint4*)(qb + ((size_t)(q0 + r) * 4 + b) * 512 + hg * 256 + coff);
        if (tid < 113) { uint4 z = {0, 0, 0, 0}; *(uint4*)&Zrow[tid * 8] = z; }
    }
    __syncthreads();

    const bf16_t* q0p = (row16 < 8) ? &Qs[row16][hl + quad * 8] : &Zrow[0];
    const bf16_t* q1p = (row16 < 8) ? &Qs[row16][hl + 32 + quad * 8] : &Zrow[8];
    const bf16x8 aq0 = *(const bf16x8*)q0p;
    const bf16x8 aq1 = *(const bf16x8*)q1p;

    float l[4] = {0.f, 0.f, 0.f, 0.f};
    for (int c = 0; c < 7; c++) {
        const int cb = c * 128;
#pragma unroll
        for (int t8 = 0; t8 < 8; t8++) {
            int key = us + cb + t8 * 16 + row16;
            int key_eff = key > 4095 ? 4095 : key;
            const bf16_t* kr = kb + (size_t)key_eff * 2048 + (size_t)b * 512 + hoffg;
            bf16x8 bk0 = *(const bf16x8*)(kr + quad * 8);
            bf16x8 bk1 = *(const bf16x8*)(kr + 32 + quad * 8);
            f32x4 acc = {};
            acc = __builtin_amdgcn_mfma_f32_16x16x32_bf16(aq0, bk0, acc, 0, 0, 0);
            acc = __builtin_amdgcn_mfma_f32_16x16x32_bf16(aq1, bk1, acc, 0, 0, 0);
#pragma unroll
            for (int r = 0; r < 4; r++) {
                int ql = quad * 4 + r;
                bool valid = (key >= sq[r]) && (key < eq[r]);
                float p = valid ? __expf(0.125f * acc[r]) : 0.0f;
                l[r] += p;
                if (ql < 8) Ps[w][ql][cb + t8 * 16 + row16] = __float2bfloat16(p);
            }
        }
    }
#pragma unroll
    for (int off = 1; off < 16; off <<= 1) {
#pragma unroll
        for (int r = 0; r < 4; r++) l[r] += __shfl_xor(l[r], off, 64);
    }
    float linv[4];
#pragma unroll
    for (int r = 0; r < 4; r++) linv[r] = 1.0f / l[r];
    if (row16 == 0) {
#pragma unroll
        for (int r = 0; r < 4; r++) {
            int ql = quad * 4 + r;
            if (ql < 8) Ls[w][ql] = linv[r];
        }
    }
    __syncthreads();

    {
        int qq = tid >> 5;
        int ln2 = tid & 31;
        float ls0 = Ls[0][qq] * 0.125f, ls1 = Ls[1][qq] * 0.125f;
        float ls2 = Ls[2][qq] * 0.125f, ls3 = Ls[3][qq] * 0.125f;
        float* base = attn_out + ((size_t)b * LQ + q0 + qq) * LK + us;
        const int cmax = LK - us;
        for (int col = ln2; col < 896; col += 32) {
            if (col < cmax) {
                float s = ls0 * tofl(Ps[0][qq][col]) + ls1 * tofl(Ps[1][qq][col]) +
                          ls2 * tofl(Ps[2][qq][col]) + ls3 * tofl(Ps[3][qq][col]);
                atomicAdd(base + col, s);
            }
        }
    }

    f32x4 o[4] = {};
    for (int c = 0; c < 7; c++) {
        const int cb = c * 128;
#pragma unroll
        for (int kt2 = 0; kt2 < 4; kt2++) {
            const bf16_t* ap_src = (row16 < 8) ? &Ps[w][row16][cb + kt2 * 32 + quad * 8]
                                               : &Zrow[0];
            bf16x8 ap = *(const bf16x8*)ap_src;
#pragma unroll
            for (int nt = 0; nt < 4; nt++) {
                const bf16_t* vr = vT + ((size_t)b * 512 + hoffg + nt * 16 + row16) * 4096
                                   + us + cb + kt2 * 32 + quad * 8;
                bf16x8 bv = *(const bf16x8*)vr;
                o[nt] = __builtin_amdgcn_mfma_f32_16x16x32_bf16(ap, bv, o[nt], 0, 0, 0);
            }
        }
    }
#pragma unroll
    for (int nt = 0; nt < 4; nt++) {
#pragma unroll
        for (int r = 0; r < 4; r++) {
            int ql = quad * 4 + r;
            if (ql < 8) {
                ctx[((size_t)(q0 + ql) * 4 + b) * 512 + hoffg + nt * 16 + row16] =
                    __float2bfloat16(o[nt][r] * linv[r]);
            }
        }
    }
}

extern "C" void kernel_launch(void* const* d_in, const int* in_sizes, int n_in,
                              void* d_out, int out_size, void* d_ws, size_t ws_size,
                              hipStream_t stream) {
    const float* tgt    = (const float*)d_in[0];
    const float* memory = (const float*)d_in[1];
    const float* Wq = (const float*)d_in[2];
    const float* bq = (const float*)d_in[3];
    const float* Wk = (const float*)d_in[4];
    const float* bk = (const float*)d_in[5];
    const float* Wv = (const float*)d_in[6];
    const float* bv = (const float*)d_in[7];
    const float* Wo = (const float*)d_in[8];
    const float* bo = (const float*)d_in[9];
    const float* W1 = (const float*)d_in[10];
    const float* b1 = (const float*)d_in[11];
    const float* W2 = (const float*)d_in[12];
    const float* b2 = (const float*)d_in[13];
    const float* ln1w = (const float*)d_in[14];
    const float* ln1b = (const float*)d_in[15];
    const float* ln2w = (const float*)d_in[16];
    const float* ln2b = (const float*)d_in[17];
    const float* ln3w = (const float*)d_in[18];
    const float* ln3b = (const float*)d_in[19];
    const float* ln4w = (const float*)d_in[20];
    const float* ln4b = (const float*)d_in[21];

    const size_t M1 = (size_t)LQ * BATCH;      // 2048
    const size_t M2 = (size_t)LK * BATCH;      // 16384
    const size_t SZ1 = M1 * DMODEL;

    // ---- workspace map (64 MiB, lifetime-aliased) ----
    // [0,16): m_buf -> vT -> {h_buf[0,8), xln_f[8,12), x2_buf[12,16)}
    // [16,32): k_buf      [32,48): v_buf -> xres[32,36)
    // [48,50): t_bf -> xln_bf    [50,54): t_f32
    // [54,56): q_bf    [56,58): W2_bf    [58,60): ctx_buf
    // [60,62): wqkvo   [62,64): W1_bf
    char* wsb = (char*)d_ws;
    const size_t MB = 1 << 20;
    bf16_t* m_buf   = (bf16_t*)(wsb + 0 * MB);
    bf16_t* vT_buf  = (bf16_t*)(wsb + 0 * MB);
    bf16_t* h_buf   = (bf16_t*)(wsb + 0 * MB);
    float*  xln_f   = (float*)(wsb + 8 * MB);
    float*  x2_buf  = (float*)(wsb + 12 * MB);
    bf16_t* k_buf   = (bf16_t*)(wsb + 16 * MB);
    bf16_t* v_buf   = (bf16_t*)(wsb + 32 * MB);
    float*  xres    = (float*)(wsb + 32 * MB);   // after transpose (v dead)
    bf16_t* t_bf    = (bf16_t*)(wsb + 48 * MB);
    bf16_t* xln_bf  = (bf16_t*)(wsb + 48 * MB);
    float*  t_f32   = (float*)(wsb + 50 * MB);
    bf16_t* q_bf    = (bf16_t*)(wsb + 54 * MB);
    bf16_t* W2_bf   = (bf16_t*)(wsb + 56 * MB);
    bf16_t* ctx_buf = (bf16_t*)(wsb + 58 * MB);
    bf16_t* wqkvo   = (bf16_t*)(wsb + 60 * MB);
    bf16_t* W1_bf   = (bf16_t*)(wsb + 62 * MB);

    bf16_t* Wq_bf = wqkvo;
    bf16_t* Wk_bf = wqkvo + 262144;
    bf16_t* Wv_bf = wqkvo + 2 * 262144;
    bf16_t* Wo_bf = wqkvo + 3 * 262144;

    float* out_x    = (float*)d_out;
    float* out_attn = out_x + SZ1;

    // 1. all conversions + attn_out zero
    prep_kernel<<<dim3(11264), dim3(256), 0, stream>>>(
        Wq, Wk, Wv, Wo, W1, W2, wqkvo, W1_bf, W2_bf, out_attn);

    // 2. LN1 (dual) + LN2 fused
    ln12_kernel<<<dim3(M1 + M2), dim3(256), 0, stream>>>(
        tgt, memory, ln1w, ln1b, ln2w, ln2b, t_bf, t_f32, m_buf);

    // 3-5. projections
    gemm_mfma<64, bf16_t, false, false><<<dim3(8, 16), dim3(256), 0, stream>>>(
        t_bf, Wq_bf, bq, nullptr, q_bf, M1, DMODEL, DMODEL);
    gemm_mfma<128, bf16_t, false, false><<<dim3(4, 128), dim3(256), 0, stream>>>(
        m_buf, Wk_bf, bk, nullptr, k_buf, M2, DMODEL, DMODEL);
    gemm_mfma<128, bf16_t, false, false><<<dim3(4, 128), dim3(256), 0, stream>>>(
        m_buf, Wv_bf, bv, nullptr, v_buf, M2, DMODEL, DMODEL);

    // 6. V transpose to [b][d][key] (m_buf dead -> vT region)
    transpose_kv<<<dim3(64, 8, 4), dim3(256), 0, stream>>>(v_buf, vT_buf);

    // 7. attention
    attn_mfma<<<dim3(512), dim3(256), 0, stream>>>(q_bf, k_buf, vT_buf, ctx_buf, out_attn);

    // 8. out proj + residual(t) -> xres (v_buf region, dead)
    gemm_mfma<64, float, false, true><<<dim3(8, 16), dim3(256), 0, stream>>>(
        ctx_buf, Wo_bf, bo, t_f32, xres, M1, DMODEL, DMODEL);

    // 9. LN3 (dual)
    ln_kernel<bf16_t, true><<<dim3(M1), dim3(256), 0, stream>>>(xres, ln3w, ln3b, xln_bf, xln_f);

    // 10. FF1 (relu)
    gemm_mfma<128, bf16_t, true, false><<<dim3(16, 16), dim3(256), 0, stream>>>(
        xln_bf, W1_bf, b1, nullptr, h_buf, M1, DFF, DMODEL);

    // 11. FF2 + residual(xln)
    gemm_mfma<64, float, false, true><<<dim3(8, 16), dim3(256), 0, stream>>>(
        h_buf, W2_bf, b2, xln_f, x2_buf, M1, DMODEL, DFF);

    // 12. LN4 -> fp32 out
    ln_kernel<float, false><<<dim3(M1), dim3(256), 0, stream>>>(x2_buf, ln4w, ln4b, out_x, nullptr);
}

// Round 11
// 333.321 us; speedup vs baseline: 1.1183x; 1.1183x over previous
//
#include <hip/hip_runtime.h>
#include <hip/hip_bf16.h>

typedef __hip_bfloat16 bf16_t;
typedef __bf16 bf16x8 __attribute__((ext_vector_type(8)));
typedef float f32x4 __attribute__((ext_vector_type(4)));

#define LQ 512
#define LK 4096
#define BATCH 4
#define DMODEL 512
#define NHEAD 8
#define HEADDIM 64
#define DFF 2048
#define LN_EPS 1e-5f

__device__ inline float tofl(float x) { return x; }
__device__ inline float tofl(bf16_t x) { return __bfloat162float(x); }
__device__ inline void stfl(float* p, float v) { *p = v; }
__device__ inline void stfl(bf16_t* p, float v) { *p = __float2bfloat16(v); }

// async global->LDS 16B copy: LDS dest = wave-uniform base + lane*16
__device__ __forceinline__ void gld_lds16(const bf16_t* g, void* lds_base) {
    __builtin_amdgcn_global_load_lds(
        (const __attribute__((address_space(1))) uint32_t*)g,
        (__attribute__((address_space(3))) uint32_t*)lds_base, 16, 0, 0);
}

// ---------- prep: all weight conversions + attn_out zero-fill ----------
__global__ void prep_kernel(const float* __restrict__ s0, const float* __restrict__ s1,
                            const float* __restrict__ s2, const float* __restrict__ s3,
                            const float* __restrict__ s4, const float* __restrict__ s5,
                            bf16_t* __restrict__ wqkvo, bf16_t* __restrict__ w1bf,
                            bf16_t* __restrict__ w2bf, float* __restrict__ zbuf) {
    int bid = blockIdx.x;
    int tid = threadIdx.x;
    if (bid < 3072) {
        int t = bid * 256 + tid;
        int which = t >> 16;            // 0..11, 262144 elements each
        int idx = (t & 65535) * 4;
        const float* s; bf16_t* d;
        if (which < 4) {
            s = (which == 0 ? s0 : which == 1 ? s1 : which == 2 ? s2 : s3) ;
            d = wqkvo + (size_t)which * 262144;
        } else if (which < 8) {
            s = s4 + (size_t)(which - 4) * 262144;
            d = w1bf + (size_t)(which - 4) * 262144;
        } else {
            s = s5 + (size_t)(which - 8) * 262144;
            d = w2bf + (size_t)(which - 8) * 262144;
        }
        float4 v = *(const float4*)(s + idx);
        d[idx + 0] = __float2bfloat16(v.x);
        d[idx + 1] = __float2bfloat16(v.y);
        d[idx + 2] = __float2bfloat16(v.z);
        d[idx + 3] = __float2bfloat16(v.w);
    } else {
        size_t i = ((size_t)(bid - 3072) * 256 + tid) * 4;
        float4 z = {0.f, 0.f, 0.f, 0.f};
        *(float4*)(zbuf + i) = z;
    }
}

// ---------- LayerNorm (generic, templated) ----------
template <typename TOUT, bool DUAL>
__global__ void ln_kernel(const float* __restrict__ in, const float* __restrict__ w,
                          const float* __restrict__ b, TOUT* __restrict__ out1,
                          float* __restrict__ out2) {
    __shared__ float red[256];
    const int row = blockIdx.x;
    const int tid = threadIdx.x;
    const float* x = in + (size_t)row * DMODEL;
    float v0 = x[tid];
    float v1 = x[tid + 256];

    red[tid] = v0 + v1;
    __syncthreads();
    for (int s = 128; s > 0; s >>= 1) { if (tid < s) red[tid] += red[tid + s]; __syncthreads(); }
    float mu = red[0] * (1.0f / DMODEL);
    __syncthreads();

    float d0 = v0 - mu, d1 = v1 - mu;
    red[tid] = d0 * d0 + d1 * d1;
    __syncthreads();
    for (int s = 128; s > 0; s >>= 1) { if (tid < s) red[tid] += red[tid + s]; __syncthreads(); }
    float inv = rsqrtf(red[0] * (1.0f / DMODEL) + LN_EPS);

    float r0 = d0 * inv * w[tid] + b[tid];
    float r1 = d1 * inv * w[tid + 256] + b[tid + 256];
    TOUT* o = out1 + (size_t)row * DMODEL;
    stfl(&o[tid], r0);
    stfl(&o[tid + 256], r1);
    if (DUAL) {
        float* o2 = out2 + (size_t)row * DMODEL;
        o2[tid] = r0;
        o2[tid + 256] = r1;
    }
}

// ---------- fused LN1 + LN2 ----------
__global__ void ln12_kernel(const float* __restrict__ tgt, const float* __restrict__ memory,
                            const float* __restrict__ w1, const float* __restrict__ b1,
                            const float* __restrict__ w2, const float* __restrict__ b2,
                            bf16_t* __restrict__ t_bf, float* __restrict__ t_f32,
                            bf16_t* __restrict__ m_buf) {
    __shared__ float red[256];
    const int row = blockIdx.x;
    const int tid = threadIdx.x;
    const float* in; const float* w; const float* b;
    bf16_t* o1; float* o2; bool dual;
    if (row < 2048) {
        in = tgt + (size_t)row * DMODEL; w = w1; b = b1;
        o1 = t_bf + (size_t)row * DMODEL; o2 = t_f32 + (size_t)row * DMODEL; dual = true;
    } else {
        int r2 = row - 2048;
        in = memory + (size_t)r2 * DMODEL; w = w2; b = b2;
        o1 = m_buf + (size_t)r2 * DMODEL; o2 = nullptr; dual = false;
    }
    float v0 = in[tid];
    float v1 = in[tid + 256];
    red[tid] = v0 + v1;
    __syncthreads();
    for (int s = 128; s > 0; s >>= 1) { if (tid < s) red[tid] += red[tid + s]; __syncthreads(); }
    float mu = red[0] * (1.0f / DMODEL);
    __syncthreads();
    float d0 = v0 - mu, d1 = v1 - mu;
    red[tid] = d0 * d0 + d1 * d1;
    __syncthreads();
    for (int s = 128; s > 0; s >>= 1) { if (tid < s) red[tid] += red[tid + s]; __syncthreads(); }
    float inv = rsqrtf(red[0] * (1.0f / DMODEL) + LN_EPS);
    float r0 = d0 * inv * w[tid] + b[tid];
    float r1 = d1 * inv * w[tid + 256] + b[tid + 256];
    o1[tid] = __float2bfloat16(r0);
    o1[tid + 256] = __float2bfloat16(r1);
    if (dual) {
        o2[tid] = r0;
        o2[tid + 256] = r1;
    }
}

// ---------- MFMA GEMM, coalesced+swizzled global_load_lds staging ----------
// Tile 128 x TN (TN=128 or 64), BK=64.
// Staging: per wave-issue lane i -> row base_r+(i>>3), chunk kc=(i&7)^(i>>3);
//   8 lanes cover one row's contiguous 128B (permuted) -> 8 transactions/wave.
// LDS layout: [r][kcs] row-major (kcs = kc ^ (r&7)); frag read XOR-deswizzles ->
//   all-32-bank ds_read_b128 (2-way only, free).
template <int TN, typename TC, bool RELU, bool RESID>
__global__ __launch_bounds__(256) void gemm_mfma(
        const bf16_t* __restrict__ A, const bf16_t* __restrict__ B,
        const float* __restrict__ bias, const float* __restrict__ resid,
        TC* __restrict__ C, int M, int N, int K) {
    __shared__ uint4 As4[1024];          // 128 rows x 8 chunks
    __shared__ uint4 Bs4[TN * 8];        // TN rows x 8 chunks

    const int tid = threadIdx.x;
    const int lane = tid & 63;
    const int wave = tid >> 6;
    const int row16 = lane & 15;
    const int quad = lane >> 4;
    const int n0 = blockIdx.x * TN;
    const int m0 = blockIdx.y * 128;

    constexpr int MI = (TN == 128) ? 4 : 2;           // 16-row frags per wave in M
    const int wy = (TN == 128) ? (wave >> 1) : wave;
    const int wx = (TN == 128) ? (wave & 1) : 0;
    const int m_base = wy * ((TN == 128) ? 64 : 32);
    const int n_base = wx * 64;

    const int rr = lane >> 3;            // 0..7 (row within issue)
    const int kc = (lane & 7) ^ rr;      // swizzled global k-chunk
    const int kx = row16 & 7;            // frag-read deswizzle key

    const bf16_t* AsE = (const bf16_t*)As4;
    const bf16_t* BsE = (const bf16_t*)Bs4;

    f32x4 acc[MI][4] = {};

    for (int k0 = 0; k0 < K; k0 += 64) {
        // stage A: 16 issues x 8 rows
#pragma unroll
        for (int it = 0; it < 4; it++) {
            int issue = it * 4 + wave;
            int r = issue * 8 + rr;
            gld_lds16(A + (size_t)(m0 + r) * K + k0 + kc * 8, &As4[issue * 64]);
        }
        // stage B: TN/8 issues
#pragma unroll
        for (int it = 0; it < TN / 32; it++) {
            int issue = it * 4 + wave;
            int r = issue * 8 + rr;
            gld_lds16(B + (size_t)(n0 + r) * K + k0 + kc * 8, &Bs4[issue * 64]);
        }
        __syncthreads();
#pragma unroll
        for (int s = 0; s < 2; s++) {
            const int kq = s * 4 + quad;
            const int kcs = (kq ^ kx) * 8;
            bf16x8 af[MI], bfr[4];
#pragma unroll
            for (int i = 0; i < MI; i++)
                af[i] = *(const bf16x8*)&AsE[(m_base + i * 16 + row16) * 64 + kcs];
#pragma unroll
            for (int j = 0; j < 4; j++)
                bfr[j] = *(const bf16x8*)&BsE[(n_base + j * 16 + row16) * 64 + kcs];
#pragma unroll
            for (int i = 0; i < MI; i++)
#pragma unroll
                for (int j = 0; j < 4; j++)
                    acc[i][j] = __builtin_amdgcn_mfma_f32_16x16x32_bf16(af[i], bfr[j], acc[i][j], 0, 0, 0);
        }
        __syncthreads();
    }

#pragma unroll
    for (int i = 0; i < MI; i++) {
#pragma unroll
        for (int j = 0; j < 4; j++) {
            int col = n0 + n_base + j * 16 + row16;
            float bsv = bias[col];
#pragma unroll
            for (int r = 0; r < 4; r++) {
                int row = m0 + m_base + i * 16 + quad * 4 + r;
                float val = acc[i][j][r] + bsv;
                if (RESID) val += resid[(size_t)row * N + col];
                if (RELU) val = fmaxf(val, 0.0f);
                stfl(&C[(size_t)row * N + col], val);
            }
        }
    }
}

// ---------- transpose: in[(key*4+b)*512 + c] -> out[(b*512+c)*4096 + key] ----------
__global__ __launch_bounds__(256) void transpose_kv(const bf16_t* __restrict__ kb,
                                                    bf16_t* __restrict__ kT) {
    __shared__ bf16_t tile[64][80];
    const int kt = blockIdx.x * 64;
    const int ct = blockIdx.y * 64;
    const int b  = blockIdx.z;
    const int t = threadIdx.x;
    {
        int kl = t >> 2, cl = (t & 3) * 16;
        const bf16_t* src = kb + ((size_t)(kt + kl) * 4 + b) * 512 + ct + cl;
        *(uint4*)&tile[kl][cl]     = *(const uint4*)src;
        *(uint4*)&tile[kl][cl + 8] = *(const uint4*)(src + 8);
    }
    __syncthreads();
    {
        int cl2 = t >> 2, ks = (t & 3) * 16;
        __attribute__((aligned(16))) bf16_t vals[16];
#pragma unroll
        for (int j = 0; j < 16; j++) vals[j] = tile[ks + j][cl2];
        bf16_t* dst = kT + ((size_t)b * 512 + ct + cl2) * 4096 + kt + ks;
        *(uint4*)dst       = *(const uint4*)&vals[0];
        *(uint4*)(dst + 8) = *(const uint4*)&vals[8];
    }
}

// ---------- MFMA flash attention, single pass (unchanged from R9) ----------
__global__ __launch_bounds__(256, 2) void attn_mfma(
        const bf16_t* __restrict__ qb,   // [2048,512] rows (q*4+b)
        const bf16_t* __restrict__ kb,   // [16384,512] rows (key*4+b)
        const bf16_t* __restrict__ vT,   // [4][512][4096]
        bf16_t* __restrict__ ctx,        // [2048,512]
        float* __restrict__ attn_out) {  // [4][512][4096], pre-zeroed
    const int d = blockIdx.x;
    const int g = d & 7;
    const int b = g >> 1;
    const int qhalf = g & 1;
    const int i_in = d >> 3;
    const int hg = i_in & 1;
    const int qt = qhalf * 32 + (i_in >> 1);
    const int q0 = qt * 8;
    const int tid = threadIdx.x;
    const int lane = tid & 63;
    const int w = tid >> 6;
    const int h = hg * 4 + w;
    const int hoffg = h * HEADDIM;
    const int hl = w * HEADDIM;
    const int row16 = lane & 15;
    const int quad = lane >> 4;

    __align__(16) __shared__ bf16_t Qs[8][264];
    __align__(16) __shared__ bf16_t Zrow[904];
    __align__(16) __shared__ bf16_t Ps[4][8][904];
    __shared__ float Ls[4][8];

    int us; { int s = q0 * 8, e = s + 827; if (e > 4095) s = 3268; us = s; }
    int sq[4], eq[4];
#pragma unroll
    for (int r = 0; r < 4; r++) {
        int ql = quad * 4 + r;
        if (ql < 8) {
            int s = (q0 + ql) * 8, e = s + 827;
            if (e > 4095) { s = 3268; e = 4096; }
            sq[r] = s; eq[r] = e;
        } else { sq[r] = 0; eq[r] = 0; }
    }

    {
        int r = tid >> 5, coff = (tid & 31) * 8;
        *(uint4*)&Qs[r][coff] =
            *(const uint4*)(qb + ((size_t)(q0 + r) * 4 + b) * 512 + hg * 256 + coff);
        if (tid < 113) { uint4 z = {0, 0, 0, 0}; *(uint4*)&Zrow[tid * 8] = z; }
    }
    __syncthreads();

    const bf16_t* q0p = (row16 < 8) ? &Qs[row16][hl + quad * 8] : &Zrow[0];
    const bf16_t* q1p = (row16 < 8) ? &Qs[row16][hl + 32 + quad * 8] : &Zrow[8];
    const bf16x8 aq0 = *(const bf16x8*)q0p;
    const bf16x8 aq1 = *(const bf16x8*)q1p;

    float l[4] = {0.f, 0.f, 0.f, 0.f};
    for (int c = 0; c < 7; c++) {
        const int cb = c * 128;
#pragma unroll
        for (int t8 = 0; t8 < 8; t8++) {
            int key = us + cb + t8 * 16 + row16;
            int key_eff = key > 4095 ? 4095 : key;
            const bf16_t* kr = kb + (size_t)key_eff * 2048 + (size_t)b * 512 + hoffg;
            bf16x8 bk0 = *(const bf16x8*)(kr + quad * 8);
            bf16x8 bk1 = *(const bf16x8*)(kr + 32 + quad * 8);
            f32x4 acc = {};
            acc = __builtin_amdgcn_mfma_f32_16x16x32_bf16(aq0, bk0, acc, 0, 0, 0);
            acc = __builtin_amdgcn_mfma_f32_16x16x32_bf16(aq1, bk1, acc, 0, 0, 0);
#pragma unroll
            for (int r = 0; r < 4; r++) {
                int ql = quad * 4 + r;
                bool valid = (key >= sq[r]) && (key < eq[r]);
                float p = valid ? __expf(0.125f * acc[r]) : 0.0f;
                l[r] += p;
                if (ql < 8) Ps[w][ql][cb + t8 * 16 + row16] = __float2bfloat16(p);
            }
        }
    }
#pragma unroll
    for (int off = 1; off < 16; off <<= 1) {
#pragma unroll
        for (int r = 0; r < 4; r++) l[r] += __shfl_xor(l[r], off, 64);
    }
    float linv[4];
#pragma unroll
    for (int r = 0; r < 4; r++) linv[r] = 1.0f / l[r];
    if (row16 == 0) {
#pragma unroll
        for (int r = 0; r < 4; r++) {
            int ql = quad * 4 + r;
            if (ql < 8) Ls[w][ql] = linv[r];
        }
    }
    __syncthreads();

    {
        int qq = tid >> 5;
        int ln2 = tid & 31;
        float ls0 = Ls[0][qq] * 0.125f, ls1 = Ls[1][qq] * 0.125f;
        float ls2 = Ls[2][qq] * 0.125f, ls3 = Ls[3][qq] * 0.125f;
        float* base = attn_out + ((size_t)b * LQ + q0 + qq) * LK + us;
        const int cmax = LK - us;
        for (int col = ln2; col < 896; col += 32) {
            if (col < cmax) {
                float s = ls0 * tofl(Ps[0][qq][col]) + ls1 * tofl(Ps[1][qq][col]) +
                          ls2 * tofl(Ps[2][qq][col]) + ls3 * tofl(Ps[3][qq][col]);
                atomicAdd(base + col, s);
            }
        }
    }

    f32x4 o[4] = {};
    for (int c = 0; c < 7; c++) {
        const int cb = c * 128;
#pragma unroll
        for (int kt2 = 0; kt2 < 4; kt2++) {
            const bf16_t* ap_src = (row16 < 8) ? &Ps[w][row16][cb + kt2 * 32 + quad * 8]
                                               : &Zrow[0];
            bf16x8 ap = *(const bf16x8*)ap_src;
#pragma unroll
            for (int nt = 0; nt < 4; nt++) {
                const bf16_t* vr = vT + ((size_t)b * 512 + hoffg + nt * 16 + row16) * 4096
                                   + us + cb + kt2 * 32 + quad * 8;
                bf16x8 bv = *(const bf16x8*)vr;
                o[nt] = __builtin_amdgcn_mfma_f32_16x16x32_bf16(ap, bv, o[nt], 0, 0, 0);
            }
        }
    }
#pragma unroll
    for (int nt = 0; nt < 4; nt++) {
#pragma unroll
        for (int r = 0; r < 4; r++) {
            int ql = quad * 4 + r;
            if (ql < 8) {
                ctx[((size_t)(q0 + ql) * 4 + b) * 512 + hoffg + nt * 16 + row16] =
                    __float2bfloat16(o[nt][r] * linv[r]);
            }
        }
    }
}

extern "C" void kernel_launch(void* const* d_in, const int* in_sizes, int n_in,
                              void* d_out, int out_size, void* d_ws, size_t ws_size,
                              hipStream_t stream) {
    const float* tgt    = (const float*)d_in[0];
    const float* memory = (const float*)d_in[1];
    const float* Wq = (const float*)d_in[2];
    const float* bq = (const float*)d_in[3];
    const float* Wk = (const float*)d_in[4];
    const float* bk = (const float*)d_in[5];
    const float* Wv = (const float*)d_in[6];
    const float* bv = (const float*)d_in[7];
    const float* Wo = (const float*)d_in[8];
    const float* bo = (const float*)d_in[9];
    const float* W1 = (const float*)d_in[10];
    const float* b1 = (const float*)d_in[11];
    const float* W2 = (const float*)d_in[12];
    const float* b2 = (const float*)d_in[13];
    const float* ln1w = (const float*)d_in[14];
    const float* ln1b = (const float*)d_in[15];
    const float* ln2w = (const float*)d_in[16];
    const float* ln2b = (const float*)d_in[17];
    const float* ln3w = (const float*)d_in[18];
    const float* ln3b = (const float*)d_in[19];
    const float* ln4w = (const float*)d_in[20];
    const float* ln4b = (const float*)d_in[21];

    const size_t M1 = (size_t)LQ * BATCH;      // 2048
    const size_t M2 = (size_t)LK * BATCH;      // 16384
    const size_t SZ1 = M1 * DMODEL;

    // ---- workspace map (64 MiB, lifetime-aliased) ----
    char* wsb = (char*)d_ws;
    const size_t MB = 1 << 20;
    bf16_t* m_buf   = (bf16_t*)(wsb + 0 * MB);
    bf16_t* vT_buf  = (bf16_t*)(wsb + 0 * MB);
    bf16_t* h_buf   = (bf16_t*)(wsb + 0 * MB);
    float*  xln_f   = (float*)(wsb + 8 * MB);
    float*  x2_buf  = (float*)(wsb + 12 * MB);
    bf16_t* k_buf   = (bf16_t*)(wsb + 16 * MB);
    bf16_t* v_buf   = (bf16_t*)(wsb + 32 * MB);
    float*  xres    = (float*)(wsb + 32 * MB);   // after transpose (v dead)
    bf16_t* t_bf    = (bf16_t*)(wsb + 48 * MB);
    bf16_t* xln_bf  = (bf16_t*)(wsb + 48 * MB);
    float*  t_f32   = (float*)(wsb + 50 * MB);
    bf16_t* q_bf    = (bf16_t*)(wsb + 54 * MB);
    bf16_t* W2_bf   = (bf16_t*)(wsb + 56 * MB);
    bf16_t* ctx_buf = (bf16_t*)(wsb + 58 * MB);
    bf16_t* wqkvo   = (bf16_t*)(wsb + 60 * MB);
    bf16_t* W1_bf   = (bf16_t*)(wsb + 62 * MB);

    bf16_t* Wq_bf = wqkvo;
    bf16_t* Wk_bf = wqkvo + 262144;
    bf16_t* Wv_bf = wqkvo + 2 * 262144;
    bf16_t* Wo_bf = wqkvo + 3 * 262144;

    float* out_x    = (float*)d_out;
    float* out_attn = out_x + SZ1;

    // 1. all conversions + attn_out zero
    prep_kernel<<<dim3(11264), dim3(256), 0, stream>>>(
        Wq, Wk, Wv, Wo, W1, W2, wqkvo, W1_bf, W2_bf, out_attn);

    // 2. LN1 (dual) + LN2 fused
    ln12_kernel<<<dim3(M1 + M2), dim3(256), 0, stream>>>(
        tgt, memory, ln1w, ln1b, ln2w, ln2b, t_bf, t_f32, m_buf);

    // 3-5. projections
    gemm_mfma<64, bf16_t, false, false><<<dim3(8, 16), dim3(256), 0, stream>>>(
        t_bf, Wq_bf, bq, nullptr, q_bf, M1, DMODEL, DMODEL);
    gemm_mfma<128, bf16_t, false, false><<<dim3(4, 128), dim3(256), 0, stream>>>(
        m_buf, Wk_bf, bk, nullptr, k_buf, M2, DMODEL, DMODEL);
    gemm_mfma<128, bf16_t, false, false><<<dim3(4, 128), dim3(256), 0, stream>>>(
        m_buf, Wv_bf, bv, nullptr, v_buf, M2, DMODEL, DMODEL);

    // 6. V transpose to [b][d][key] (m_buf dead -> vT region)
    transpose_kv<<<dim3(64, 8, 4), dim3(256), 0, stream>>>(v_buf, vT_buf);

    // 7. attention
    attn_mfma<<<dim3(512), dim3(256), 0, stream>>>(q_bf, k_buf, vT_buf, ctx_buf, out_attn);

    // 8. out proj + residual(t) -> xres (v_buf region, dead)
    gemm_mfma<64, float, false, true><<<dim3(8, 16), dim3(256), 0, stream>>>(
        ctx_buf, Wo_bf, bo, t_f32, xres, M1, DMODEL, DMODEL);

    // 9. LN3 (dual)
    ln_kernel<bf16_t, true><<<dim3(M1), dim3(256), 0, stream>>>(xres, ln3w, ln3b, xln_bf, xln_f);

    // 10. FF1 (relu)
    gemm_mfma<128, bf16_t, true, false><<<dim3(16, 16), dim3(256), 0, stream>>>(
        xln_bf, W1_bf, b1, nullptr, h_buf, M1, DFF, DMODEL);

    // 11. FF2 + residual(xln)
    gemm_mfma<64, float, false, true><<<dim3(8, 16), dim3(256), 0, stream>>>(
        h_buf, W2_bf, b2, xln_f, x2_buf, M1, DMODEL, DFF);

    // 12. LN4 -> fp32 out
    ln_kernel<float, false><<<dim3(M1), dim3(256), 0, stream>>>(x2_buf, ln4w, ln4b, out_x, nullptr);
}